// Round 1
// 527.908 us; speedup vs baseline: 1.0285x; 1.0285x over previous
//
#include <hip/hip_runtime.h>
#include <hip/hip_bf16.h>
#include <stdint.h>

// QuantizedLinear NF4: x (4,2048,4096) f32, packed (4096,2048) i32 (one byte
// per int32), absmax (4096,) f32, bias (4096,) f32 -> out (4,2048,4096) f32.
#define M_DIM 8192
#define N_DIM 4096
#define K_DIM 4096

typedef __bf16 bf16_t;
typedef __attribute__((ext_vector_type(8))) __bf16 bf16x8;
typedef __attribute__((ext_vector_type(4))) __bf16 bf16x4;
typedef __attribute__((ext_vector_type(4))) float f32x4;

__constant__ float NF4_LUT[16] = {
    -1.0f, -0.6961928009986877f, -0.5250730514526367f, -0.39491748809814453f,
    -0.28444138169288635f, -0.18477343022823334f, -0.09105003625154495f, 0.0f,
    0.07958029955625534f, 0.16093020141124725f, 0.24611230194568634f,
    0.33791524171829224f, 0.44070982933044434f, 0.5626170039176941f,
    0.7229568362236023f, 1.0f};

// ---------------------------------------------------------------------------
// Kernel 1: NF4 dequant -> bf16 W (N_DIM x K_DIM row-major). Unchanged.
// ---------------------------------------------------------------------------
__global__ __launch_bounds__(256) void dequant_nf4_kernel(
    const int* __restrict__ packed, const float* __restrict__ absmax,
    bf16_t* __restrict__ W) {
  const int t = blockIdx.x * 256 + threadIdx.x;
  const int row = t >> 9;
  const int c = t & 511;
  const int lane = threadIdx.x & 63;
  const int lutbits = __float_as_int(NF4_LUT[lane & 15]);

  const int4 p = ((const int4*)packed)[t];
  const float am = absmax[row];
  bf16x8 v;
#pragma unroll
  for (int q = 0; q < 4; ++q) {
    const int byte = (q == 0 ? p.x : q == 1 ? p.y : q == 2 ? p.z : p.w) & 255;
    const float hi =
        __int_as_float(__builtin_amdgcn_ds_bpermute(((byte >> 4) & 15) << 2, lutbits));
    const float lo =
        __int_as_float(__builtin_amdgcn_ds_bpermute((byte & 15) << 2, lutbits));
    v[2 * q] = (bf16_t)(hi * am);
    v[2 * q + 1] = (bf16_t)(lo * am);
  }
  *((bf16x8*)&W[(size_t)row * K_DIM + c * 8]) = v;
}

// ---------------------------------------------------------------------------
// Kernel 2: x f32 -> bf16. Unchanged.
// ---------------------------------------------------------------------------
__global__ __launch_bounds__(256) void cvt_bf16_kernel(
    const float* __restrict__ x, bf16_t* __restrict__ y) {
  const int t = blockIdx.x * 256 + threadIdx.x;
  const float4 a = ((const float4*)x)[t];
  bf16x4 v;
  v[0] = (bf16_t)a.x; v[1] = (bf16_t)a.y; v[2] = (bf16_t)a.z; v[3] = (bf16_t)a.w;
  *((bf16x4*)&y[(size_t)t * 4]) = v;
}

// ---------------------------------------------------------------------------
// Kernel 3: 256x256x64 8-phase bf16 MFMA GEMM (T1+T2+T3+T4+T5 port).
//
// LDS layout (per buffer): [256 rows][8 chunks of 16B] row-major, with XOR
// swizzle at chunk granularity: physical chunk = logical chunk ^ (row & 7).
// Staging keeps the LDS destination LINEAR (global_load_lds constraint) and
// pre-swizzles the per-lane GLOBAL source; fragment ds_reads apply the same
// XOR -> 2-way bank aliasing (free).
//
// Region lifetimes within a K-tile (phases = quadrants (mh,nh) in order
// (0,0),(0,1),(1,0),(1,1); A-frags read once per mh and reused):
//   G_A1 = A rows {0-63,128-191}    last LDS-read phase 0
//   G_A2 = A rows {64-127,192-255}  last LDS-read phase 2
//   G_B1 = B rows {s*64+0..31}      last LDS-read phase 2
//   G_B2 = B rows {s*64+32..63}     last LDS-read phase 3
// Stage schedule for tile t:  p0: G_A2(t+1)->other buf (dead since t-1 p2)
//                             p1: G_B2(t+1)->other buf (dead since t-1 p3)
//                             p2: G_A1(t+2)->this buf  (dead since p0)
//                             p3: G_B1(t+2)->this buf  (dead since p2)
// All prefetch targets are barrier-separated from their last reader.
// vmcnt(4) once per K-tile retires everything except the two t+2-group
// stages -> all of tile t+1 is guaranteed in LDS; 2-3 half-tiles stay in
// flight across barriers (never vmcnt(0) in the main loop).
// ---------------------------------------------------------------------------
#define GLD_LDS16(g, l)                                                     \
  __builtin_amdgcn_global_load_lds(                                        \
      (const __attribute__((address_space(1))) void*)(g),                   \
      (__attribute__((address_space(3))) void*)(l), 16, 0, 0)

#define MFMA_BF16(a, b, c) \
  __builtin_amdgcn_mfma_f32_16x16x32_bf16((a), (b), (c), 0, 0, 0)

#define STAGE_A1(tt, lds)                                    \
  do {                                                       \
    GLD_LDS16(gA1a + (size_t)(tt) * 64, (lds) + dA0);        \
    GLD_LDS16(gA1b + (size_t)(tt) * 64, (lds) + dA0 + 16384);\
  } while (0)
#define STAGE_A2(tt, lds)                                    \
  do {                                                       \
    GLD_LDS16(gA2a + (size_t)(tt) * 64, (lds) + dA0 + 8192); \
    GLD_LDS16(gA2b + (size_t)(tt) * 64, (lds) + dA0 + 24576);\
  } while (0)
#define STAGE_B1(tt, lds)                                    \
  do {                                                       \
    GLD_LDS16(gB1a + (size_t)(tt) * 64, (lds) + dB0);        \
    GLD_LDS16(gB1b + (size_t)(tt) * 64, (lds) + dB0 + 16384);\
  } while (0)
#define STAGE_B2(tt, lds)                                    \
  do {                                                       \
    GLD_LDS16(gB2a + (size_t)(tt) * 64, (lds) + dB0 + 4096); \
    GLD_LDS16(gB2b + (size_t)(tt) * 64, (lds) + dB0 + 20480);\
  } while (0)

#define END_BARRIER()                \
  asm volatile("" ::: "memory");     \
  __builtin_amdgcn_s_barrier();      \
  asm volatile("" ::: "memory")

#define MID_BARRIER()                                   \
  asm volatile("" ::: "memory");                        \
  __builtin_amdgcn_s_barrier();                         \
  asm volatile("s_waitcnt lgkmcnt(0)" ::: "memory");    \
  __builtin_amdgcn_sched_barrier(0)

__global__ __launch_bounds__(512, 2) void gemm_nf4_kernel(
    const bf16_t* __restrict__ A, const bf16_t* __restrict__ B,
    const float* __restrict__ bias, float* __restrict__ C) {
  constexpr int NT = K_DIM / 64;
  __shared__ __align__(16) bf16_t sA[2][256 * 64];  // 2 x 32 KiB
  __shared__ __align__(16) bf16_t sB[2][256 * 64];  // 2 x 32 KiB

  const int tid = threadIdx.x;
  const int wave = tid >> 6, lane = tid & 63;
  const int wm = wave >> 2, wn = wave & 3;  // 2 x 4 wave grid
  const int quad = lane >> 4, l15 = lane & 15, l7 = lane & 7;

  // T1: XCD-aware block swizzle (512 blocks, 512 % 8 == 0 -> bijective).
  const int id = (blockIdx.x & 7) * 64 + (blockIdx.x >> 3);
  const int blockM = (id & 31) * 256;  // 32 M-blocks
  const int blockN = (id >> 5) * 256;  // 16 N-blocks

  // ---- staging addresses (linear LDS dest, pre-swizzled global source) ----
  const int rqa = tid >> 3;                       // row in 64-row quarter
  const int cira = ((tid & 7) ^ (rqa & 7)) * 8;   // swizzled chunk -> elements
  const bf16_t* gA1a = A + (size_t)(blockM + rqa) * K_DIM + cira;
  const bf16_t* gA1b = gA1a + (size_t)128 * K_DIM;
  const bf16_t* gA2a = gA1a + (size_t)64 * K_DIM;
  const bf16_t* gA2b = gA1a + (size_t)192 * K_DIM;
  const int s0 = tid >> 8, cis = tid & 255;       // B: strip, chunk-in-strip
  const int rqb = cis >> 3;                       // row in 32-row strip
  const int cirb = ((cis & 7) ^ (rqb & 7)) * 8;
  const bf16_t* gB1a = B + (size_t)(blockN + s0 * 64 + rqb) * K_DIM + cirb;
  const bf16_t* gB1b = gB1a + (size_t)128 * K_DIM;
  const bf16_t* gB2a = gB1a + (size_t)32 * K_DIM;
  const bf16_t* gB2b = gB1a + (size_t)160 * K_DIM;
  const int dA0 = tid * 16;
  const int dB0 = s0 * 8192 + cis * 16;

  // ---- fragment-read byte offsets (swizzled: chunk = (ks*4+quad)^l7) ----
  const int aRd0 = wm * 16384 + l15 * 128 + ((quad ^ l7) * 16);
  const int aRd1 = wm * 16384 + l15 * 128 + (((4 | quad) ^ l7) * 16);
  const int bRd0 = wn * 8192 + l15 * 128 + ((quad ^ l7) * 16);
  const int bRd1 = wn * 8192 + l15 * 128 + (((4 | quad) ^ l7) * 16);

  f32x4 acc[8][4];
#pragma unroll
  for (int i = 0; i < 8; ++i)
#pragma unroll
    for (int j = 0; j < 4; ++j) acc[i][j] = (f32x4)(0.0f);

  // ---- prologue: tile 0 fully + tile 1's A1/B1 groups ----
  {
    char* sa0 = (char*)sA[0];
    char* sb0 = (char*)sB[0];
    char* sa1 = (char*)sA[1];
    char* sb1 = (char*)sB[1];
    STAGE_A1(0, sa0);
    STAGE_B1(0, sb0);
    STAGE_A2(0, sa0);
    STAGE_B2(0, sb0);
    STAGE_A1(1, sa1);
    STAGE_B1(1, sb1);
    asm volatile("s_waitcnt vmcnt(4)" ::: "memory");  // tile 0 resident
    __builtin_amdgcn_s_barrier();
    asm volatile("" ::: "memory");
  }

  for (int t = 0; t < NT; ++t) {
    char* sa = (char*)sA[t & 1];
    char* sao = (char*)sA[(t + 1) & 1];
    char* sb = (char*)sB[t & 1];
    char* sbo = (char*)sB[(t + 1) & 1];

    bf16x8 af[4][2], bq[2][2];

    // ===== phase 0: quadrant (mh=0, nh=0); stage G_A2(t+1) =====
#pragma unroll
    for (int i = 0; i < 4; ++i) {
      af[i][0] = *(const bf16x8*)(sa + aRd0 + i * 2048);
      af[i][1] = *(const bf16x8*)(sa + aRd1 + i * 2048);
    }
#pragma unroll
    for (int j = 0; j < 2; ++j) {
      bq[j][0] = *(const bf16x8*)(sb + bRd0 + j * 2048);
      bq[j][1] = *(const bf16x8*)(sb + bRd1 + j * 2048);
    }
    if (t + 1 < NT) STAGE_A2(t + 1, sao);
    asm volatile("s_waitcnt lgkmcnt(8)" ::: "memory");
    MID_BARRIER();
    __builtin_amdgcn_s_setprio(1);
#pragma unroll
    for (int i = 0; i < 4; ++i)
#pragma unroll
      for (int j = 0; j < 2; ++j) {
        acc[i][j] = MFMA_BF16(af[i][0], bq[j][0], acc[i][j]);
        acc[i][j] = MFMA_BF16(af[i][1], bq[j][1], acc[i][j]);
      }
    __builtin_amdgcn_s_setprio(0);
    END_BARRIER();

    // ===== phase 1: quadrant (mh=0, nh=1); reuse af; stage G_B2(t+1) =====
#pragma unroll
    for (int j = 0; j < 2; ++j) {
      bq[j][0] = *(const bf16x8*)(sb + bRd0 + (2 + j) * 2048);
      bq[j][1] = *(const bf16x8*)(sb + bRd1 + (2 + j) * 2048);
    }
    if (t + 1 < NT) STAGE_B2(t + 1, sbo);
    MID_BARRIER();
    __builtin_amdgcn_s_setprio(1);
#pragma unroll
    for (int i = 0; i < 4; ++i)
#pragma unroll
      for (int j = 0; j < 2; ++j) {
        acc[i][2 + j] = MFMA_BF16(af[i][0], bq[j][0], acc[i][2 + j]);
        acc[i][2 + j] = MFMA_BF16(af[i][1], bq[j][1], acc[i][2 + j]);
      }
    __builtin_amdgcn_s_setprio(0);
    END_BARRIER();

    // ===== phase 2: quadrant (mh=1, nh=0); stage G_A1(t+2) =====
#pragma unroll
    for (int i = 0; i < 4; ++i) {
      af[i][0] = *(const bf16x8*)(sa + aRd0 + (4 + i) * 2048);
      af[i][1] = *(const bf16x8*)(sa + aRd1 + (4 + i) * 2048);
    }
#pragma unroll
    for (int j = 0; j < 2; ++j) {
      bq[j][0] = *(const bf16x8*)(sb + bRd0 + j * 2048);
      bq[j][1] = *(const bf16x8*)(sb + bRd1 + j * 2048);
    }
    if (t + 2 < NT) STAGE_A1(t + 2, sa);
    asm volatile("s_waitcnt lgkmcnt(8)" ::: "memory");
    MID_BARRIER();
    __builtin_amdgcn_s_setprio(1);
#pragma unroll
    for (int i = 0; i < 4; ++i)
#pragma unroll
      for (int j = 0; j < 2; ++j) {
        acc[4 + i][j] = MFMA_BF16(af[i][0], bq[j][0], acc[4 + i][j]);
        acc[4 + i][j] = MFMA_BF16(af[i][1], bq[j][1], acc[4 + i][j]);
      }
    __builtin_amdgcn_s_setprio(0);
    END_BARRIER();

    // ===== phase 3: quadrant (mh=1, nh=1); reuse af; stage G_B1(t+2) =====
#pragma unroll
    for (int j = 0; j < 2; ++j) {
      bq[j][0] = *(const bf16x8*)(sb + bRd0 + (2 + j) * 2048);
      bq[j][1] = *(const bf16x8*)(sb + bRd1 + (2 + j) * 2048);
    }
    if (t + 2 < NT) STAGE_B1(t + 2, sb);
    MID_BARRIER();
    __builtin_amdgcn_s_setprio(1);
#pragma unroll
    for (int i = 0; i < 4; ++i)
#pragma unroll
      for (int j = 0; j < 2; ++j) {
        acc[4 + i][2 + j] = MFMA_BF16(af[i][0], bq[j][0], acc[4 + i][2 + j]);
        acc[4 + i][2 + j] = MFMA_BF16(af[i][1], bq[j][1], acc[4 + i][2 + j]);
      }
    __builtin_amdgcn_s_setprio(0);
    // Counted vmcnt once per K-tile (T4): keep the two t+2-group prefetches
    // in flight across the boundary; drain fully only at the pipeline tail.
    if (t < NT - 2)
      asm volatile("s_waitcnt vmcnt(4)" ::: "memory");
    else
      asm volatile("s_waitcnt vmcnt(0)" ::: "memory");
    END_BARRIER();
  }

  // ---- epilogue: C/D layout col = lane&15 (n), row = quad*4 + reg (m) ----
#pragma unroll
  for (int nf = 0; nf < 4; ++nf) {
    const int n = blockN + wn * 64 + nf * 16 + l15;
    const float bv = bias[n];
#pragma unroll
    for (int mf = 0; mf < 8; ++mf) {
      const int m0 = blockM + wm * 128 + mf * 16 + quad * 4;
      f32x4 v = acc[mf][nf];
      C[(size_t)(m0 + 0) * N_DIM + n] = v[0] + bv;
      C[(size_t)(m0 + 1) * N_DIM + n] = v[1] + bv;
      C[(size_t)(m0 + 2) * N_DIM + n] = v[2] + bv;
      C[(size_t)(m0 + 3) * N_DIM + n] = v[3] + bv;
    }
  }
}

// ---------------------------------------------------------------------------
// Fallback (ws too small): naive on-the-fly dequant GEMM.
// ---------------------------------------------------------------------------
__global__ __launch_bounds__(256) void fallback_kernel(
    const float* __restrict__ x, const int* __restrict__ packed,
    const float* __restrict__ absmax, const float* __restrict__ bias,
    float* __restrict__ out) {
  const int idx = blockIdx.x * 256 + threadIdx.x;
  const int m = idx / N_DIM, n = idx % N_DIM;
  const int* prow = packed + (size_t)n * (K_DIM / 2);
  const float* xr = x + (size_t)m * K_DIM;
  float s = 0.0f;
  for (int p = 0; p < K_DIM / 2; ++p) {
    const int b = prow[p] & 255;
    s += xr[2 * p] * NF4_LUT[(b >> 4) & 15] + xr[2 * p + 1] * NF4_LUT[b & 15];
  }
  out[idx] = s * absmax[n] + bias[n];
}

extern "C" void kernel_launch(void* const* d_in, const int* in_sizes, int n_in,
                              void* d_out, int out_size, void* d_ws,
                              size_t ws_size, hipStream_t stream) {
  const float* x = (const float*)d_in[0];
  const int* packed = (const int*)d_in[1];
  const float* absmax = (const float*)d_in[2];
  const float* bias = (const float*)d_in[3];
  float* out = (float*)d_out;

  const size_t wBytes = (size_t)N_DIM * K_DIM * sizeof(bf16_t);  // 32 MB
  const size_t xBytes = (size_t)M_DIM * K_DIM * sizeof(bf16_t);  // 64 MB
  if (ws_size < wBytes + xBytes) {
    fallback_kernel<<<dim3((M_DIM * N_DIM) / 256), dim3(256), 0, stream>>>(
        x, packed, absmax, bias, out);
    return;
  }

  bf16_t* W = (bf16_t*)d_ws;
  bf16_t* xb = (bf16_t*)((char*)d_ws + wBytes);

  dequant_nf4_kernel<<<dim3((N_DIM * (K_DIM / 2) / 4) / 256), dim3(256), 0,
                       stream>>>(packed, absmax, W);
  cvt_bf16_kernel<<<dim3((M_DIM * K_DIM / 4) / 256), dim3(256), 0, stream>>>(
      x, xb);
  gemm_nf4_kernel<<<dim3((M_DIM / 256) * (N_DIM / 256)), dim3(512), 0,
                    stream>>>(xb, W, bias, out);
}

// Round 2
// 521.443 us; speedup vs baseline: 1.0412x; 1.0124x over previous
//
#include <hip/hip_runtime.h>
#include <hip/hip_bf16.h>
#include <stdint.h>

// QuantizedLinear NF4: x (4,2048,4096) f32, packed (4096,2048) i32 (one byte
// per int32), absmax (4096,) f32, bias (4096,) f32 -> out (4,2048,4096) f32.
#define M_DIM 8192
#define N_DIM 4096
#define K_DIM 4096

typedef __bf16 bf16_t;
typedef __attribute__((ext_vector_type(8))) __bf16 bf16x8;
typedef __attribute__((ext_vector_type(4))) __bf16 bf16x4;
typedef __attribute__((ext_vector_type(4))) float f32x4;
typedef __attribute__((ext_vector_type(16))) float f32x16;

__constant__ float NF4_LUT[16] = {
    -1.0f, -0.6961928009986877f, -0.5250730514526367f, -0.39491748809814453f,
    -0.28444138169288635f, -0.18477343022823334f, -0.09105003625154495f, 0.0f,
    0.07958029955625534f, 0.16093020141124725f, 0.24611230194568634f,
    0.33791524171829224f, 0.44070982933044434f, 0.5626170039176941f,
    0.7229568362236023f, 1.0f};

// ---------------------------------------------------------------------------
// Kernel 1: NF4 dequant -> bf16 W (N_DIM x K_DIM row-major). Unchanged.
// ---------------------------------------------------------------------------
__global__ __launch_bounds__(256) void dequant_nf4_kernel(
    const int* __restrict__ packed, const float* __restrict__ absmax,
    bf16_t* __restrict__ W) {
  const int t = blockIdx.x * 256 + threadIdx.x;
  const int row = t >> 9;
  const int c = t & 511;
  const int lane = threadIdx.x & 63;
  const int lutbits = __float_as_int(NF4_LUT[lane & 15]);

  const int4 p = ((const int4*)packed)[t];
  const float am = absmax[row];
  bf16x8 v;
#pragma unroll
  for (int q = 0; q < 4; ++q) {
    const int byte = (q == 0 ? p.x : q == 1 ? p.y : q == 2 ? p.z : p.w) & 255;
    const float hi =
        __int_as_float(__builtin_amdgcn_ds_bpermute(((byte >> 4) & 15) << 2, lutbits));
    const float lo =
        __int_as_float(__builtin_amdgcn_ds_bpermute((byte & 15) << 2, lutbits));
    v[2 * q] = (bf16_t)(hi * am);
    v[2 * q + 1] = (bf16_t)(lo * am);
  }
  *((bf16x8*)&W[(size_t)row * K_DIM + c * 8]) = v;
}

// ---------------------------------------------------------------------------
// Kernel 2: x f32 -> bf16. Unchanged.
// ---------------------------------------------------------------------------
__global__ __launch_bounds__(256) void cvt_bf16_kernel(
    const float* __restrict__ x, bf16_t* __restrict__ y) {
  const int t = blockIdx.x * 256 + threadIdx.x;
  const float4 a = ((const float4*)x)[t];
  bf16x4 v;
  v[0] = (bf16_t)a.x; v[1] = (bf16_t)a.y; v[2] = (bf16_t)a.z; v[3] = (bf16_t)a.w;
  *((bf16x4*)&y[(size_t)t * 4]) = v;
}

// ---------------------------------------------------------------------------
// Kernel 3: 256x256x64 2-phase bf16 MFMA GEMM, 32x32x16 shape.
//
// vs round 1 (4-phase, 16x16x32): each fragment is now read from LDS exactly
// ONCE per K-tile (24 ds_read_b128/wave vs 32 — B held in regs across both
// phases), barrier count halves (4/K-tile), and the 32x32x16 matrix pipe is
// ~13% faster than 16x16x32 (2382 vs 2075 TF ubench) with half the
// instruction count.
//
// LDS layout (per buffer): [256 rows][8 chunks of 16B], phys chunk =
// logical ^ (row & 7). Linear LDS dest for global_load_lds, pre-swizzled
// GLOBAL source; fragment reads apply the same XOR. Quarter-wave bank check
// for 32x32 reads: rows l&31, phys chunk (ks*2+hi)^(l&7) -> 2 lanes/bank per
// 16-lane group = conflict-free.
//
// Phase plan per K-tile t (phases = mh halves; bq covers ALL of B, held):
//   p0 (mh=0): read af0(8) + bq(8); stage A2(t+1)+B2(t+1) -> other buf
//              (dead since t-1 p1 / t-1 p0); lgkmcnt(8); bar; 16 MFMA; bar.
//   p1 (mh=1): read af1(8), reuse bq; stage A1(t+2)+B1(t+2) -> this buf
//              (A1 dead since p0, B1 dead since p0); bar; 16 MFMA;
//              vmcnt(4); bar.
// vmcnt(4) at end of tile t retires A1B1(t+1) [from t-1 p1] and A2B2(t+1)
// [from t p0] -> tile t+1 fully resident; leaves A1B1(t+2) in flight.
// Never vmcnt(0) in the main loop (T4).
// ---------------------------------------------------------------------------
#define GLD_LDS16(g, l)                                                     \
  __builtin_amdgcn_global_load_lds(                                        \
      (const __attribute__((address_space(1))) void*)(g),                   \
      (__attribute__((address_space(3))) void*)(l), 16, 0, 0)

#define MFMA32(a, b, c) \
  __builtin_amdgcn_mfma_f32_32x32x16_bf16((a), (b), (c), 0, 0, 0)

#define STAGE_A1(tt, lds)                                    \
  do {                                                       \
    GLD_LDS16(gA1a + (size_t)(tt) * 64, (lds) + dA0);        \
    GLD_LDS16(gA1b + (size_t)(tt) * 64, (lds) + dA0 + 16384);\
  } while (0)
#define STAGE_A2(tt, lds)                                    \
  do {                                                       \
    GLD_LDS16(gA2a + (size_t)(tt) * 64, (lds) + dA0 + 8192); \
    GLD_LDS16(gA2b + (size_t)(tt) * 64, (lds) + dA0 + 24576);\
  } while (0)
#define STAGE_B1(tt, lds)                                    \
  do {                                                       \
    GLD_LDS16(gB1a + (size_t)(tt) * 64, (lds) + dB0);        \
    GLD_LDS16(gB1b + (size_t)(tt) * 64, (lds) + dB0 + 16384);\
  } while (0)
#define STAGE_B2(tt, lds)                                    \
  do {                                                       \
    GLD_LDS16(gB2a + (size_t)(tt) * 64, (lds) + dB0 + 4096); \
    GLD_LDS16(gB2b + (size_t)(tt) * 64, (lds) + dB0 + 20480);\
  } while (0)

#define END_BARRIER()                \
  asm volatile("" ::: "memory");     \
  __builtin_amdgcn_s_barrier();      \
  asm volatile("" ::: "memory")

#define MID_BARRIER()                                   \
  asm volatile("" ::: "memory");                        \
  __builtin_amdgcn_s_barrier();                         \
  asm volatile("s_waitcnt lgkmcnt(0)" ::: "memory");    \
  __builtin_amdgcn_sched_barrier(0)

__global__ __launch_bounds__(512, 2) void gemm_nf4_kernel(
    const bf16_t* __restrict__ A, const bf16_t* __restrict__ B,
    const float* __restrict__ bias, float* __restrict__ C) {
  constexpr int NT = K_DIM / 64;
  __shared__ __align__(16) bf16_t sA[2][256 * 64];  // 2 x 32 KiB
  __shared__ __align__(16) bf16_t sB[2][256 * 64];  // 2 x 32 KiB

  const int tid = threadIdx.x;
  const int wave = tid >> 6, lane = tid & 63;
  const int wm = wave >> 2, wn = wave & 3;  // 2 x 4 wave grid
  const int l31 = lane & 31, hi = lane >> 5, l7 = lane & 7;

  // T1: XCD-aware block swizzle (512 blocks, 512 % 8 == 0 -> bijective).
  const int id = (blockIdx.x & 7) * 64 + (blockIdx.x >> 3);
  const int blockM = (id & 31) * 256;  // 32 M-blocks
  const int blockN = (id >> 5) * 256;  // 16 N-blocks

  // ---- staging addresses (linear LDS dest, pre-swizzled global source) ----
  const int rqa = tid >> 3;                       // row in 64-row quarter
  const int cira = ((tid & 7) ^ (rqa & 7)) * 8;   // swizzled chunk -> elements
  const bf16_t* gA1a = A + (size_t)(blockM + rqa) * K_DIM + cira;
  const bf16_t* gA1b = gA1a + (size_t)128 * K_DIM;
  const bf16_t* gA2a = gA1a + (size_t)64 * K_DIM;
  const bf16_t* gA2b = gA1a + (size_t)192 * K_DIM;
  const int s0 = tid >> 8, cis = tid & 255;       // B: strip, chunk-in-strip
  const int rqb = cis >> 3;                       // row in 32-row strip
  const int cirb = ((cis & 7) ^ (rqb & 7)) * 8;
  const bf16_t* gB1a = B + (size_t)(blockN + s0 * 64 + rqb) * K_DIM + cirb;
  const bf16_t* gB1b = gB1a + (size_t)128 * K_DIM;
  const bf16_t* gB2a = gB1a + (size_t)32 * K_DIM;
  const bf16_t* gB2b = gB1a + (size_t)160 * K_DIM;
  const int dA0 = tid * 16;
  const int dB0 = s0 * 8192 + cis * 16;

  // ---- fragment-read byte offsets ----
  // Lane reads row (base + l31), k-chunk (ks*2 + hi); phys chunk ^= (row&7)=l7.
  const int aBase = (wm * 128 + l31) * 128;  // byte offset of lane's A row
  const int bBase = (wn * 64 + l31) * 128;   // byte offset of lane's B row
  int cOff[4];
#pragma unroll
  for (int ks = 0; ks < 4; ++ks) cOff[ks] = ((ks * 2 + hi) ^ l7) * 16;

  f32x16 acc[4][2];
#pragma unroll
  for (int i = 0; i < 4; ++i)
#pragma unroll
    for (int j = 0; j < 2; ++j) acc[i][j] = (f32x16)(0.0f);

  // ---- prologue: tile 0 fully + tile 1's A1/B1 groups ----
  {
    char* sa0 = (char*)sA[0];
    char* sb0 = (char*)sB[0];
    char* sa1 = (char*)sA[1];
    char* sb1 = (char*)sB[1];
    STAGE_A1(0, sa0);
    STAGE_B1(0, sb0);
    STAGE_A2(0, sa0);
    STAGE_B2(0, sb0);
    STAGE_A1(1, sa1);
    STAGE_B1(1, sb1);
    asm volatile("s_waitcnt vmcnt(4)" ::: "memory");  // tile 0 resident
    __builtin_amdgcn_s_barrier();
    asm volatile("" ::: "memory");
  }

  for (int t = 0; t < NT; ++t) {
    char* sa = (char*)sA[t & 1];
    char* sao = (char*)sA[(t + 1) & 1];
    char* sb = (char*)sB[t & 1];
    char* sbo = (char*)sB[(t + 1) & 1];

    bf16x8 af[2][4], bq[2][4];

    // ===== phase 0: mh=0 rows; read af0 + ALL of B; stage A2/B2(t+1) =====
#pragma unroll
    for (int mt = 0; mt < 2; ++mt)
#pragma unroll
      for (int ks = 0; ks < 4; ++ks)
        af[mt][ks] = *(const bf16x8*)(sa + aBase + mt * 4096 + cOff[ks]);
#pragma unroll
    for (int nt = 0; nt < 2; ++nt)
#pragma unroll
      for (int ks = 0; ks < 4; ++ks)
        bq[nt][ks] = *(const bf16x8*)(sb + bBase + nt * 4096 + cOff[ks]);
    if (t + 1 < NT) {
      STAGE_A2(t + 1, sao);
      STAGE_B2(t + 1, sbo);
    }
    asm volatile("s_waitcnt lgkmcnt(8)" ::: "memory");
    MID_BARRIER();
    __builtin_amdgcn_s_setprio(1);
#pragma unroll
    for (int ks = 0; ks < 4; ++ks)
#pragma unroll
      for (int mt = 0; mt < 2; ++mt)
#pragma unroll
        for (int nt = 0; nt < 2; ++nt)
          acc[mt][nt] = MFMA32(af[mt][ks], bq[nt][ks], acc[mt][nt]);
    __builtin_amdgcn_s_setprio(0);
    END_BARRIER();

    // ===== phase 1: mh=1 rows; read af1, reuse bq; stage A1/B1(t+2) =====
#pragma unroll
    for (int mt = 0; mt < 2; ++mt)
#pragma unroll
      for (int ks = 0; ks < 4; ++ks)
        af[mt][ks] = *(const bf16x8*)(sa + aBase + 8192 + mt * 4096 + cOff[ks]);
    if (t + 2 < NT) {
      STAGE_A1(t + 2, sa);
      STAGE_B1(t + 2, sb);
    }
    MID_BARRIER();
    __builtin_amdgcn_s_setprio(1);
#pragma unroll
    for (int ks = 0; ks < 4; ++ks)
#pragma unroll
      for (int mt = 0; mt < 2; ++mt)
#pragma unroll
        for (int nt = 0; nt < 2; ++nt)
          acc[2 + mt][nt] = MFMA32(af[mt][ks], bq[nt][ks], acc[2 + mt][nt]);
    __builtin_amdgcn_s_setprio(0);
    // Counted vmcnt once per K-tile (T4): retire A1B1(t+1)+A2B2(t+1), keep
    // A1B1(t+2) in flight. Full drain only at the pipeline tail.
    if (t < NT - 2)
      asm volatile("s_waitcnt vmcnt(4)" ::: "memory");
    else
      asm volatile("s_waitcnt vmcnt(0)" ::: "memory");
    END_BARRIER();
  }

  // ---- epilogue: 32x32 C/D: col = l31, row = (reg&3)+8*(reg>>2)+4*hi ----
#pragma unroll
  for (int nt = 0; nt < 2; ++nt) {
    const int n = blockN + wn * 64 + nt * 32 + l31;
    const float bv = bias[n];
#pragma unroll
    for (int mt = 0; mt < 4; ++mt) {
      const int mbase = blockM + wm * 128 + mt * 32 + hi * 4;
      f32x16 v = acc[mt][nt];
#pragma unroll
      for (int r = 0; r < 16; ++r) {
        const int m = mbase + (r & 3) + 8 * (r >> 2);
        C[(size_t)m * N_DIM + n] = v[r] + bv;
      }
    }
  }
}

// ---------------------------------------------------------------------------
// Fallback (ws too small): naive on-the-fly dequant GEMM.
// ---------------------------------------------------------------------------
__global__ __launch_bounds__(256) void fallback_kernel(
    const float* __restrict__ x, const int* __restrict__ packed,
    const float* __restrict__ absmax, const float* __restrict__ bias,
    float* __restrict__ out) {
  const int idx = blockIdx.x * 256 + threadIdx.x;
  const int m = idx / N_DIM, n = idx % N_DIM;
  const int* prow = packed + (size_t)n * (K_DIM / 2);
  const float* xr = x + (size_t)m * K_DIM;
  float s = 0.0f;
  for (int p = 0; p < K_DIM / 2; ++p) {
    const int b = prow[p] & 255;
    s += xr[2 * p] * NF4_LUT[(b >> 4) & 15] + xr[2 * p + 1] * NF4_LUT[b & 15];
  }
  out[idx] = s * absmax[n] + bias[n];
}

extern "C" void kernel_launch(void* const* d_in, const int* in_sizes, int n_in,
                              void* d_out, int out_size, void* d_ws,
                              size_t ws_size, hipStream_t stream) {
  const float* x = (const float*)d_in[0];
  const int* packed = (const int*)d_in[1];
  const float* absmax = (const float*)d_in[2];
  const float* bias = (const float*)d_in[3];
  float* out = (float*)d_out;

  const size_t wBytes = (size_t)N_DIM * K_DIM * sizeof(bf16_t);  // 32 MB
  const size_t xBytes = (size_t)M_DIM * K_DIM * sizeof(bf16_t);  // 64 MB
  if (ws_size < wBytes + xBytes) {
    fallback_kernel<<<dim3((M_DIM * N_DIM) / 256), dim3(256), 0, stream>>>(
        x, packed, absmax, bias, out);
    return;
  }

  bf16_t* W = (bf16_t*)d_ws;
  bf16_t* xb = (bf16_t*)((char*)d_ws + wBytes);

  dequant_nf4_kernel<<<dim3((N_DIM * (K_DIM / 2) / 4) / 256), dim3(256), 0,
                       stream>>>(packed, absmax, W);
  cvt_bf16_kernel<<<dim3((M_DIM * K_DIM / 4) / 256), dim3(256), 0, stream>>>(
      x, xb);
  gemm_nf4_kernel<<<dim3((M_DIM / 256) * (N_DIM / 256)), dim3(512), 0,
                    stream>>>(xb, W, bias, out);
}

// Round 3
// 479.633 us; speedup vs baseline: 1.1320x; 1.0872x over previous
//
#include <hip/hip_runtime.h>
#include <hip/hip_bf16.h>
#include <stdint.h>

// QuantizedLinear NF4: x (4,2048,4096) f32, packed (4096,2048) i32 (one byte
// per int32), absmax (4096,) f32, bias (4096,) f32 -> out (4,2048,4096) f32.
#define M_DIM 8192
#define N_DIM 4096
#define K_DIM 4096

typedef __bf16 bf16_t;
typedef __attribute__((ext_vector_type(8))) __bf16 bf16x8;
typedef __attribute__((ext_vector_type(4))) __bf16 bf16x4;
typedef __attribute__((ext_vector_type(4))) float f32x4;

__constant__ float NF4_LUT[16] = {
    -1.0f, -0.6961928009986877f, -0.5250730514526367f, -0.39491748809814453f,
    -0.28444138169288635f, -0.18477343022823334f, -0.09105003625154495f, 0.0f,
    0.07958029955625534f, 0.16093020141124725f, 0.24611230194568634f,
    0.33791524171829224f, 0.44070982933044434f, 0.5626170039176941f,
    0.7229568362236023f, 1.0f};

// ---------------------------------------------------------------------------
// Kernel 1 (fused): NF4 dequant -> bf16 W  AND  x f32 -> bf16.
// Grid partition: blocks [0, DQ_BLOCKS) do dequant, the rest convert x.
// (One launch instead of two — probing the ~220us of non-GEMM time.)
// ---------------------------------------------------------------------------
#define DQ_BLOCKS ((N_DIM * (K_DIM / 2) / 4) / 256)   // 8192
#define CVT_BLOCKS ((M_DIM * K_DIM / 4) / 256)        // 8192

__global__ __launch_bounds__(256) void prep_kernel(
    const int* __restrict__ packed, const float* __restrict__ absmax,
    bf16_t* __restrict__ W, const float* __restrict__ x,
    bf16_t* __restrict__ y) {
  if (blockIdx.x < DQ_BLOCKS) {
    const int t = blockIdx.x * 256 + threadIdx.x;
    const int row = t >> 9;
    const int c = t & 511;
    const int lane = threadIdx.x & 63;
    const int lutbits = __float_as_int(NF4_LUT[lane & 15]);

    const int4 p = ((const int4*)packed)[t];
    const float am = absmax[row];
    bf16x8 v;
#pragma unroll
    for (int q = 0; q < 4; ++q) {
      const int byte = (q == 0 ? p.x : q == 1 ? p.y : q == 2 ? p.z : p.w) & 255;
      const float hi = __int_as_float(
          __builtin_amdgcn_ds_bpermute(((byte >> 4) & 15) << 2, lutbits));
      const float lo = __int_as_float(
          __builtin_amdgcn_ds_bpermute((byte & 15) << 2, lutbits));
      v[2 * q] = (bf16_t)(hi * am);
      v[2 * q + 1] = (bf16_t)(lo * am);
    }
    *((bf16x8*)&W[(size_t)row * K_DIM + c * 8]) = v;
  } else {
    const int t = (blockIdx.x - DQ_BLOCKS) * 256 + threadIdx.x;
    const float4 a = ((const float4*)x)[t];
    bf16x4 v;
    v[0] = (bf16_t)a.x; v[1] = (bf16_t)a.y;
    v[2] = (bf16_t)a.z; v[3] = (bf16_t)a.w;
    *((bf16x4*)&y[(size_t)t * 4]) = v;
  }
}

// ---------------------------------------------------------------------------
// Kernel 2: 256x256x64 2-phase bf16 MFMA GEMM, 16x16x32 shape.
//
// Round-2 post-mortem: the 32x32 fragment geometry (row = lane&31) produced
// 2.5e7 LDS bank conflicts on the same layout where round-1's 16x16 geometry
// (row = base + l15, slot = (kc*4+quad)^l7) measured EXACTLY 0. This round
// keeps round-2's reduced-read 2-phase schedule but reverts the fragment
// geometry to the empirically-conflict-free 16x16 functions, and removes the
// two mid-tile barriers (hazard analysis below) -> 2 barriers per K-tile.
//
// LDS: [2 buf][256 rows][8 chunks of 16B], phys chunk = logical ^ (row&7).
// Linear LDS dest for global_load_lds; pre-swizzled GLOBAL source.
//
// Regions (per buffer):  A1 = rows {0-63,128-191}   A2 = rows {64-127,192-255}
//                        B1 = rows {s*64+0..31}     B2 = rows {s*64+32..63}
// Per K-tile t:
//   p0: read af rows (wm*128 + 0..63)  [= A1]  (8x b128)
//       read bq rows (wn*64 + 0..63)   [= B1+B2] (8x b128)
//       stage A2(t+1)+B2(t+1) -> other buf (last read: tile t-1, sep by its
//       tile-end barrier);  BARRIER;  lgkmcnt(0);  32 MFMA (acc[0..3][*]).
//   p1: read af rows +64 [= A2] (8x b128)  — no barrier: reads of cur have no
//       hazard with p0's work;
//       stage A1(t+2)+B1(t+2) -> cur buf. Hazard vs all waves' p0 READS of
//       A1/B1(cur): separated by the p0 barrier (all waves passed it before
//       any wave stages).  lgkmcnt(0);  32 MFMA (acc[4..7][*]).
//       vmcnt(4): retires A1B1(t+1) [issued t-1 p1] + A2B2(t+1) [t p0],
//       leaves A1B1(t+2) in flight (never vmcnt(0) mid-loop).
//       TILE-END BARRIER: all waves' tile-(t+1) staging retired before any
//       wave reads it.
// ---------------------------------------------------------------------------
#define GLD_LDS16(g, l)                                                     \
  __builtin_amdgcn_global_load_lds(                                        \
      (const __attribute__((address_space(1))) void*)(g),                   \
      (__attribute__((address_space(3))) void*)(l), 16, 0, 0)

#define MFMA16(a, b, c) \
  __builtin_amdgcn_mfma_f32_16x16x32_bf16((a), (b), (c), 0, 0, 0)

#define STAGE_A1(tt, lds)                                    \
  do {                                                       \
    GLD_LDS16(gA1a + (size_t)(tt) * 64, (lds) + dA0);        \
    GLD_LDS16(gA1b + (size_t)(tt) * 64, (lds) + dA0 + 16384);\
  } while (0)
#define STAGE_A2(tt, lds)                                    \
  do {                                                       \
    GLD_LDS16(gA2a + (size_t)(tt) * 64, (lds) + dA0 + 8192); \
    GLD_LDS16(gA2b + (size_t)(tt) * 64, (lds) + dA0 + 24576);\
  } while (0)
#define STAGE_B1(tt, lds)                                    \
  do {                                                       \
    GLD_LDS16(gB1a + (size_t)(tt) * 64, (lds) + dB0);        \
    GLD_LDS16(gB1b + (size_t)(tt) * 64, (lds) + dB0 + 16384);\
  } while (0)
#define STAGE_B2(tt, lds)                                    \
  do {                                                       \
    GLD_LDS16(gB2a + (size_t)(tt) * 64, (lds) + dB0 + 4096); \
    GLD_LDS16(gB2b + (size_t)(tt) * 64, (lds) + dB0 + 20480);\
  } while (0)

#define BARRIER()                    \
  asm volatile("" ::: "memory");     \
  __builtin_amdgcn_s_barrier();      \
  asm volatile("" ::: "memory")

#define LGKM0_FENCE()                                   \
  asm volatile("s_waitcnt lgkmcnt(0)" ::: "memory");    \
  __builtin_amdgcn_sched_barrier(0)

__global__ __launch_bounds__(512, 2) void gemm_nf4_kernel(
    const bf16_t* __restrict__ A, const bf16_t* __restrict__ B,
    const float* __restrict__ bias, float* __restrict__ C) {
  constexpr int NT = K_DIM / 64;
  __shared__ __align__(16) bf16_t sA[2][256 * 64];  // 2 x 32 KiB
  __shared__ __align__(16) bf16_t sB[2][256 * 64];  // 2 x 32 KiB

  const int tid = threadIdx.x;
  const int wave = tid >> 6, lane = tid & 63;
  const int wm = wave >> 2, wn = wave & 3;  // 2 x 4 wave grid
  const int quad = lane >> 4, l15 = lane & 15, l7 = lane & 7;

  // T1: XCD-aware block swizzle (512 blocks, 512 % 8 == 0 -> bijective).
  const int id = (blockIdx.x & 7) * 64 + (blockIdx.x >> 3);
  const int blockM = (id & 31) * 256;  // 32 M-blocks
  const int blockN = (id >> 5) * 256;  // 16 N-blocks

  // ---- staging addresses (linear LDS dest, pre-swizzled global source) ----
  const int rqa = tid >> 3;                       // row in 64-row quarter
  const int cira = ((tid & 7) ^ (rqa & 7)) * 8;   // swizzled chunk -> elements
  const bf16_t* gA1a = A + (size_t)(blockM + rqa) * K_DIM + cira;
  const bf16_t* gA1b = gA1a + (size_t)128 * K_DIM;
  const bf16_t* gA2a = gA1a + (size_t)64 * K_DIM;
  const bf16_t* gA2b = gA1a + (size_t)192 * K_DIM;
  const int s0 = tid >> 8, cis = tid & 255;       // B: strip, chunk-in-strip
  const int rqb = cis >> 3;                       // row in 32-row strip
  const int cirb = ((cis & 7) ^ (rqb & 7)) * 8;
  const bf16_t* gB1a = B + (size_t)(blockN + s0 * 64 + rqb) * K_DIM + cirb;
  const bf16_t* gB1b = gB1a + (size_t)128 * K_DIM;
  const bf16_t* gB2a = gB1a + (size_t)32 * K_DIM;
  const bf16_t* gB2b = gB1a + (size_t)160 * K_DIM;
  const int dA0 = tid * 16;
  const int dB0 = s0 * 8192 + cis * 16;

  // ---- fragment-read byte offsets (round-1 geometry, measured 0 conflicts)
  // Lane reads row (base + i*16 + l15), logical chunk kc*4+quad,
  // phys slot = (kc*4+quad) ^ l7  (row&7 = l7).
  const int aBase = (wm * 128 + l15) * 128;
  const int bBase = (wn * 64 + l15) * 128;
  const int sl0 = (quad ^ l7) * 16;        // kc = 0
  const int sl1 = ((4 | quad) ^ l7) * 16;  // kc = 1

  f32x4 acc[8][4];
#pragma unroll
  for (int i = 0; i < 8; ++i)
#pragma unroll
    for (int j = 0; j < 4; ++j) acc[i][j] = (f32x4)(0.0f);

  // ---- prologue: tile 0 fully + tile 1's A1/B1 groups ----
  {
    char* sa0 = (char*)sA[0];
    char* sb0 = (char*)sB[0];
    char* sa1 = (char*)sA[1];
    char* sb1 = (char*)sB[1];
    STAGE_A1(0, sa0);
    STAGE_B1(0, sb0);
    STAGE_A2(0, sa0);
    STAGE_B2(0, sb0);
    STAGE_A1(1, sa1);
    STAGE_B1(1, sb1);
    asm volatile("s_waitcnt vmcnt(4)" ::: "memory");  // tile 0 resident
    __builtin_amdgcn_s_barrier();
    asm volatile("" ::: "memory");
  }

  for (int t = 0; t < NT; ++t) {
    char* sa = (char*)sA[t & 1];
    char* sao = (char*)sA[(t + 1) & 1];
    char* sb = (char*)sB[t & 1];
    char* sbo = (char*)sB[(t + 1) & 1];

    bf16x8 af[4][2], bq[4][2];

    // ===== phase 0: A rows (wm*128 + 0..63) + ALL B; stage A2/B2(t+1) =====
#pragma unroll
    for (int i = 0; i < 4; ++i) {
      af[i][0] = *(const bf16x8*)(sa + aBase + i * 2048 + sl0);
      af[i][1] = *(const bf16x8*)(sa + aBase + i * 2048 + sl1);
    }
#pragma unroll
    for (int j = 0; j < 4; ++j) {
      bq[j][0] = *(const bf16x8*)(sb + bBase + j * 2048 + sl0);
      bq[j][1] = *(const bf16x8*)(sb + bBase + j * 2048 + sl1);
    }
    if (t + 1 < NT) {
      STAGE_A2(t + 1, sao);
      STAGE_B2(t + 1, sbo);
    }
    BARRIER();
    LGKM0_FENCE();
    __builtin_amdgcn_s_setprio(1);
#pragma unroll
    for (int i = 0; i < 4; ++i)
#pragma unroll
      for (int j = 0; j < 4; ++j) {
        acc[i][j] = MFMA16(af[i][0], bq[j][0], acc[i][j]);
        acc[i][j] = MFMA16(af[i][1], bq[j][1], acc[i][j]);
      }
    __builtin_amdgcn_s_setprio(0);

    // ===== phase 1 (no barrier): A rows +64; reuse bq; stage A1/B1(t+2) ====
#pragma unroll
    for (int i = 0; i < 4; ++i) {
      af[i][0] = *(const bf16x8*)(sa + aBase + 8192 + i * 2048 + sl0);
      af[i][1] = *(const bf16x8*)(sa + aBase + 8192 + i * 2048 + sl1);
    }
    if (t + 2 < NT) {
      STAGE_A1(t + 2, sa);
      STAGE_B1(t + 2, sb);
    }
    LGKM0_FENCE();
    __builtin_amdgcn_s_setprio(1);
#pragma unroll
    for (int i = 0; i < 4; ++i)
#pragma unroll
      for (int j = 0; j < 4; ++j) {
        acc[4 + i][j] = MFMA16(af[i][0], bq[j][0], acc[4 + i][j]);
        acc[4 + i][j] = MFMA16(af[i][1], bq[j][1], acc[4 + i][j]);
      }
    __builtin_amdgcn_s_setprio(0);
    // Counted vmcnt (T4): retire tile-(t+1) staging, keep A1B1(t+2) in
    // flight. Full drain only at the pipeline tail.
    if (t < NT - 2)
      asm volatile("s_waitcnt vmcnt(4)" ::: "memory");
    else
      asm volatile("s_waitcnt vmcnt(0)" ::: "memory");
    BARRIER();
  }

  // ---- epilogue: C/D layout col = l15 (n), row = quad*4 + reg (m) ----
#pragma unroll
  for (int j = 0; j < 4; ++j) {
    const int n = blockN + wn * 64 + j * 16 + l15;
    const float bv = bias[n];
#pragma unroll
    for (int i = 0; i < 8; ++i) {
      const int m0 = blockM + wm * 128 + i * 16 + quad * 4;
      f32x4 v = acc[i][j];
      C[(size_t)(m0 + 0) * N_DIM + n] = v[0] + bv;
      C[(size_t)(m0 + 1) * N_DIM + n] = v[1] + bv;
      C[(size_t)(m0 + 2) * N_DIM + n] = v[2] + bv;
      C[(size_t)(m0 + 3) * N_DIM + n] = v[3] + bv;
    }
  }
}

// ---------------------------------------------------------------------------
// Fallback (ws too small): naive on-the-fly dequant GEMM.
// ---------------------------------------------------------------------------
__global__ __launch_bounds__(256) void fallback_kernel(
    const float* __restrict__ x, const int* __restrict__ packed,
    const float* __restrict__ absmax, const float* __restrict__ bias,
    float* __restrict__ out) {
  const int idx = blockIdx.x * 256 + threadIdx.x;
  const int m = idx / N_DIM, n = idx % N_DIM;
  const int* prow = packed + (size_t)n * (K_DIM / 2);
  const float* xr = x + (size_t)m * K_DIM;
  float s = 0.0f;
  for (int p = 0; p < K_DIM / 2; ++p) {
    const int b = prow[p] & 255;
    s += xr[2 * p] * NF4_LUT[(b >> 4) & 15] + xr[2 * p + 1] * NF4_LUT[b & 15];
  }
  out[idx] = s * absmax[n] + bias[n];
}

extern "C" void kernel_launch(void* const* d_in, const int* in_sizes, int n_in,
                              void* d_out, int out_size, void* d_ws,
                              size_t ws_size, hipStream_t stream) {
  const float* x = (const float*)d_in[0];
  const int* packed = (const int*)d_in[1];
  const float* absmax = (const float*)d_in[2];
  const float* bias = (const float*)d_in[3];
  float* out = (float*)d_out;

  const size_t wBytes = (size_t)N_DIM * K_DIM * sizeof(bf16_t);  // 32 MB
  const size_t xBytes = (size_t)M_DIM * K_DIM * sizeof(bf16_t);  // 64 MB
  if (ws_size < wBytes + xBytes) {
    fallback_kernel<<<dim3((M_DIM * N_DIM) / 256), dim3(256), 0, stream>>>(
        x, packed, absmax, bias, out);
    return;
  }

  bf16_t* W = (bf16_t*)d_ws;
  bf16_t* xb = (bf16_t*)((char*)d_ws + wBytes);

  prep_kernel<<<dim3(DQ_BLOCKS + CVT_BLOCKS), dim3(256), 0, stream>>>(
      packed, absmax, W, x, xb);
  gemm_nf4_kernel<<<dim3((M_DIM / 256) * (N_DIM / 256)), dim3(512), 0,
                    stream>>>(xb, W, bias, out);
}